// Round 16
// baseline (504.974 us; speedup 1.0000x reference)
//
#include <hip/hip_runtime.h>
#include <math.h>

#ifndef M_PI
#define M_PI 3.14159265358979323846
#endif

static inline int cdiv(int a, int b){ return (a + b - 1) / b; }

#define SQRT3f  1.7320508075688772f
#define SQRT5f  2.23606797749979f
#define SQRT15f 3.872983346207417f
#define KRADf   0.6324555320336759f      /* sqrt(2/R_MAX), R_MAX=5 */
#define PI5f    0.6283185307179586f      /* pi/5 */

// sum over the 16-lane channel group (within-group, xor 1..8)
__device__ __forceinline__ float grp16_sum(float v){
  v += __shfl_xor(v, 1, 64);
  v += __shfl_xor(v, 2, 64);
  v += __shfl_xor(v, 4, 64);
  v += __shfl_xor(v, 8, 64);
  return v;
}
// sum across the 4 groups of a wave (same channel lane in each group)
__device__ __forceinline__ float xgrp_sum(float v){
  v += __shfl_xor(v, 16, 64);
  v += __shfl_xor(v, 32, 64);
  return v;
}

// sh from unit vector (8 ops)
__device__ __forceinline__ void sh_from_u(float ux, float uy, float uz,
                                          float* sh1, float* sh2)
{
  sh1[0] = SQRT3f*ux; sh1[1] = SQRT3f*uy; sh1[2] = SQRT3f*uz;
  sh2[0] = SQRT15f*ux*uy;
  sh2[1] = SQRT15f*uy*uz;
  sh2[2] = 0.5f*SQRT5f*(3.f*uz*uz - 1.f);
  sh2[3] = SQRT15f*ux*uz;
  sh2[4] = 0.5f*SQRT15f*(ux*ux - uy*uy);
}

// Chebyshev recurrences from (s1,c1)=sincos(pi*r/5): rad only (fwd)
__device__ __forceinline__ void rad_from_sc(float s1, float c1, float inv_r, float* rad)
{
  float tc = 2.f * c1;
  float sprev = 0.f, s = s1;
  float Ki = KRADf * inv_r;
  #pragma unroll
  for (int k = 0; k < 8; k++) {
    rad[k] = Ki * s;
    float sn = tc*s - sprev; sprev = s; s = sn;
  }
}
// rad + draddr (bwd)
__device__ __forceinline__ void rad_drad_from_sc(float s1, float c1, float inv_r,
                                                 float* rad, float* draddr)
{
  float tc = 2.f * c1;
  float sprev = 0.f, s = s1, cprev = 1.f, cc = c1;
  float Ki = KRADf * inv_r;
  const float KPI5 = KRADf * PI5f;
  #pragma unroll
  for (int k = 0; k < 8; k++) {
    rad[k] = Ki * s;
    draddr[k] = (KPI5 * (float)(k+1) * cc - rad[k]) * inv_r;
    float sn = tc*s - sprev; sprev = s; s = sn;
    float cn = tc*cc - cprev; cprev = cc; cc = cn;
  }
}

// ---------------------------------------------------------------------------
// Degree histogram (E-parallel)
// ---------------------------------------------------------------------------
__global__ void k_hist(const int* __restrict__ ei, int E,
                       int* __restrict__ deg_row, int* __restrict__ deg_col)
{
  int e = blockIdx.x * blockDim.x + threadIdx.x;
  if (e >= E) return;
  atomicAdd(&deg_row[ei[e]], 1);
  atomicAdd(&deg_col[ei[E + e]], 1);
}

// ---------------------------------------------------------------------------
// Scan-free segment allocation: wave-aggregated atomicAdd on global cursors.
// ---------------------------------------------------------------------------
__global__ void k_alloc(const int* __restrict__ deg_row, const int* __restrict__ deg_col,
                        int* __restrict__ start_row, int* __restrict__ cur_row,
                        int* __restrict__ start_col, int* __restrict__ cur_col,
                        int* __restrict__ cursors, int N)
{
  int idx = blockIdx.x * blockDim.x + threadIdx.x;
  int lane = threadIdx.x & 63;
  #pragma unroll
  for (int which = 0; which < 2; which++) {
    const int* deg = which ? deg_col : deg_row;
    int* start = which ? start_col : start_row;
    int* cur   = which ? cur_col   : cur_row;
    int v = (idx < N) ? deg[idx] : 0;
    int incl = v;
    #pragma unroll
    for (int d = 1; d < 64; d <<= 1) {
      int y = __shfl_up(incl, d, 64);
      if (lane >= d) incl += y;
    }
    int wtot = __shfl(incl, 63, 64);
    int base = 0;
    if (lane == 63) base = atomicAdd(&cursors[which], wtot);
    base = __shfl(base, 63, 64);
    if (idx < N) { int st = base + incl - v; start[idx] = st; cur[idx] = st; }
  }
}

// ---------------------------------------------------------------------------
// Scatter + compact geometry. Row order: u + (s1,c1) (fwd kernels + bwd_b0
// recompute rad/draddr). Col order: u + PRECOMPUTED rad[8]+draddr[8] streams
// (rdC, 4xfloat4/edge) — removes the ~40-op recurrence from the hottest
// kernel (k_bwd_b1_col, VALU-bound at 65%).
// ---------------------------------------------------------------------------
__global__ void k_scatter_geom(const float* __restrict__ pos, const int* __restrict__ ei, int E,
                               int* __restrict__ cur_row, int* __restrict__ cur_col,
                               float4* __restrict__ uR, float2* __restrict__ scR,
                               float4* __restrict__ uC, float4* __restrict__ rdC,
                               int* __restrict__ colR, int* __restrict__ cposR,
                               int* __restrict__ rowC, int* __restrict__ rposC)
{
  int e = blockIdx.x * blockDim.x + threadIdx.x;
  if (e >= E) return;
  int row = ei[e], col = ei[E + e];
  int pr = atomicAdd(&cur_row[row], 1);
  int pc = atomicAdd(&cur_col[col], 1);
  colR[pr] = col; cposR[pr] = pc;
  rowC[pc] = row; rposC[pc] = pr;

  float px = pos[row*3+0] - pos[col*3+0];
  float py = pos[row*3+1] - pos[col*3+1];
  float pz = pos[row*3+2] - pos[col*3+2];
  float r2 = px*px + py*py + pz*pz + 1e-12f;
  float r = sqrtf(r2);
  float inv_r = 1.0f / r;
  float ux = px*inv_r, uy = py*inv_r, uz = pz*inv_r;
  float s1, c1;
  sincosf(r * PI5f, &s1, &c1);
  float4 u4 = make_float4(ux, uy, uz, inv_r);
  uR[pr] = u4; scR[pr] = make_float2(s1, c1);
  uC[pc] = u4;
  float rad[8], draddr[8];
  rad_drad_from_sc(s1, c1, inv_r, rad, draddr);
  rdC[pc*4+0] = make_float4(rad[0], rad[1], rad[2], rad[3]);
  rdC[pc*4+1] = make_float4(rad[4], rad[5], rad[6], rad[7]);
  rdC[pc*4+2] = make_float4(draddr[0], draddr[1], draddr[2], draddr[3]);
  rdC[pc*4+3] = make_float4(draddr[4], draddr[5], draddr[6], draddr[7]);
}

// ---------------------------------------------------------------------------
// h0_init[n,:] = emb[z[n],:] @ W_init
// ---------------------------------------------------------------------------
__global__ void k_node_init(const float* __restrict__ emb, const int* __restrict__ z,
                            const float* __restrict__ W_init, float* __restrict__ h0, int N)
{
  __shared__ float sW[256];
  if (threadIdx.x < 256) sW[threadIdx.x] = W_init[threadIdx.x];
  __syncthreads();
  int n = blockIdx.x * blockDim.x + threadIdx.x;
  if (n >= N) return;
  const float* e = emb + z[n]*16;
  float ev[16];
  #pragma unroll
  for (int k = 0; k < 16; k++) ev[k] = e[k];
  #pragma unroll
  for (int c = 0; c < 16; c++) {
    float s = 0.f;
    #pragma unroll
    for (int k = 0; k < 16; k++) s += ev[k] * sW[k*16+c];
    h0[n*16+c] = s;
  }
}

// ---------------------------------------------------------------------------
// Forward block 0 — wave per node (4 groups x 16 channels, stride-4 edges).
// ---------------------------------------------------------------------------
__global__ void k_fwd_b0(const float* __restrict__ Wr, const float* __restrict__ br,
                         const float* __restrict__ h0_in,
                         const float4* __restrict__ uR, const float2* __restrict__ scR,
                         const int* __restrict__ colR,
                         const int* __restrict__ start_row, const int* __restrict__ deg_row,
                         float* __restrict__ a0, float* __restrict__ a1, float* __restrict__ a2,
                         int N)
{
  int n = (blockIdx.x * blockDim.x + threadIdx.x) >> 6;
  int lane = threadIdx.x & 63;
  int g = lane >> 4, c = lane & 15;
  if (n >= N) return;
  float wr0[8], wr1[8], wr2[8];
  #pragma unroll
  for (int k = 0; k < 8; k++) {
    wr0[k] = Wr[k*80 + c];
    wr1[k] = Wr[k*80 + 16 + c];
    wr2[k] = Wr[k*80 + 32 + c];
  }
  float b0v = br[c], b1v = br[16 + c], b2v = br[32 + c];

  float acc0 = 0.f, acc1[3] = {0.f,0.f,0.f}, acc2[5] = {0.f,0.f,0.f,0.f,0.f};

  int i0 = start_row[n] + g, i1 = start_row[n] + deg_row[n];
  float4 Un = {0,0,0,0}; float2 SCn = {0,0};
  float h0n = 0.f;
  if (i0 < i1) {
    Un = uR[i0]; SCn = scR[i0];
    h0n = h0_in[colR[i0]*16 + c];
  }
  for (int i = i0; i < i1; i += 4) {
    float4 U = Un; float2 SC = SCn;
    float h0c = h0n;
    if (i+4 < i1) {
      Un = uR[i+4]; SCn = scR[i+4];
      h0n = h0_in[colR[i+4]*16 + c];
    }
    float rad[8];
    rad_from_sc(SC.x, SC.y, U.w, rad);
    float sh1[3], sh2[5];
    sh_from_u(U.x, U.y, U.z, sh1, sh2);
    float w0 = b0v, w1 = b1v, w2 = b2v;
    #pragma unroll
    for (int k = 0; k < 8; k++) {
      w0 += rad[k]*wr0[k]; w1 += rad[k]*wr1[k]; w2 += rad[k]*wr2[k];
    }
    acc0 += w0*h0c;
    float wh1 = w1*h0c, wh2 = w2*h0c;
    #pragma unroll
    for (int m = 0; m < 3; m++) acc1[m] += wh1*sh1[m];
    #pragma unroll
    for (int m = 0; m < 5; m++) acc2[m] += wh2*sh2[m];
  }
  acc0 = xgrp_sum(acc0);
  #pragma unroll
  for (int m = 0; m < 3; m++) acc1[m] = xgrp_sum(acc1[m]);
  #pragma unroll
  for (int m = 0; m < 5; m++) acc2[m] = xgrp_sum(acc2[m]);
  if (g == 0) {
    a0[n*16 + c] = acc0;
    #pragma unroll
    for (int m = 0; m < 3; m++) a1[n*48 + c*3 + m] = acc1[m];
    #pragma unroll
    for (int m = 0; m < 5; m++) a2[n*80 + c*5 + m] = acc2[m];
  }
}

// ---------------------------------------------------------------------------
// Forward block 1 (last) — wave per node.
// ---------------------------------------------------------------------------
__global__ void k_fwd_b1(const float* __restrict__ Wr, const float* __restrict__ br,
                         const float* __restrict__ h0_in, const float* __restrict__ h1_in,
                         const float* __restrict__ h2_in,
                         const float4* __restrict__ uR, const float2* __restrict__ scR,
                         const int* __restrict__ colR,
                         const int* __restrict__ start_row, const int* __restrict__ deg_row,
                         float* __restrict__ a0, int N)
{
  int n = (blockIdx.x * blockDim.x + threadIdx.x) >> 6;
  int lane = threadIdx.x & 63;
  int g = lane >> 4, c = lane & 15;
  if (n >= N) return;
  float wr0[8], wr3[8], wr4[8];
  #pragma unroll
  for (int k = 0; k < 8; k++) {
    wr0[k] = Wr[k*80 + c];
    wr3[k] = Wr[k*80 + 48 + c];
    wr4[k] = Wr[k*80 + 64 + c];
  }
  float b0v = br[c], b3v = br[48 + c], b4v = br[64 + c];

  float acc0 = 0.f;
  int i0 = start_row[n] + g, i1 = start_row[n] + deg_row[n];
  float4 Un = {0,0,0,0}; float2 SCn = {0,0};
  float h0n = 0.f, h1n[3] = {0,0,0}, h2n[5] = {0,0,0,0,0};
  if (i0 < i1) {
    int col = colR[i0];
    Un = uR[i0]; SCn = scR[i0];
    h0n = h0_in[col*16 + c];
    #pragma unroll
    for (int m = 0; m < 3; m++) h1n[m] = h1_in[col*48 + c*3 + m];
    #pragma unroll
    for (int m = 0; m < 5; m++) h2n[m] = h2_in[col*80 + c*5 + m];
  }
  for (int i = i0; i < i1; i += 4) {
    float4 U = Un; float2 SC = SCn;
    float h0c = h0n;
    float h1c[3], h2c[5];
    #pragma unroll
    for (int m = 0; m < 3; m++) h1c[m] = h1n[m];
    #pragma unroll
    for (int m = 0; m < 5; m++) h2c[m] = h2n[m];
    if (i+4 < i1) {
      int col = colR[i+4];
      Un = uR[i+4]; SCn = scR[i+4];
      h0n = h0_in[col*16 + c];
      #pragma unroll
      for (int m = 0; m < 3; m++) h1n[m] = h1_in[col*48 + c*3 + m];
      #pragma unroll
      for (int m = 0; m < 5; m++) h2n[m] = h2_in[col*80 + c*5 + m];
    }
    float rad[8];
    rad_from_sc(SC.x, SC.y, U.w, rad);
    float sh1[3], sh2[5];
    sh_from_u(U.x, U.y, U.z, sh1, sh2);
    float w0 = b0v, w3 = b3v, w4 = b4v;
    #pragma unroll
    for (int k = 0; k < 8; k++) {
      w0 += rad[k]*wr0[k]; w3 += rad[k]*wr3[k]; w4 += rad[k]*wr4[k];
    }
    float S1 = 0.f, S2 = 0.f;
    #pragma unroll
    for (int m = 0; m < 3; m++) S1 += h1c[m]*sh1[m];
    #pragma unroll
    for (int m = 0; m < 5; m++) S2 += h2c[m]*sh2[m];
    acc0 += w0*h0c + w3*S1 + w4*S2;
  }
  acc0 = xgrp_sum(acc0);
  if (g == 0) a0[n*16 + c] = acc0;
}

// ---------------------------------------------------------------------------
// Node update (block 0 only): h_out = h_in + a @ U
// ---------------------------------------------------------------------------
__global__ void k_node_update(const float* __restrict__ h0_in,
                              const float* __restrict__ a0, const float* __restrict__ a1,
                              const float* __restrict__ a2,
                              const float* __restrict__ U,
                              float* __restrict__ h0_out, float* __restrict__ h1_out,
                              float* __restrict__ h2_out, int N)
{
  int idx = blockIdx.x * blockDim.x + threadIdx.x;
  int n = idx >> 4, d = idx & 15;
  if (n >= N) return;
  const float* U0 = U;
  const float* U1 = U + 256;
  const float* U2 = U + 512;
  float s = h0_in[n*16 + d];
  #pragma unroll
  for (int c = 0; c < 16; c++) s += a0[n*16 + c] * U0[c*16 + d];
  h0_out[n*16 + d] = s;
  float v1[3] = {0.f, 0.f, 0.f};
  #pragma unroll
  for (int c = 0; c < 16; c++) {
    float u = U1[c*16 + d];
    #pragma unroll
    for (int m = 0; m < 3; m++) v1[m] += a1[n*48 + c*3 + m] * u;
  }
  #pragma unroll
  for (int m = 0; m < 3; m++) h1_out[n*48 + d*3 + m] = v1[m];
  float v2[5] = {0.f, 0.f, 0.f, 0.f, 0.f};
  #pragma unroll
  for (int c = 0; c < 16; c++) {
    float u = U2[c*16 + d];
    #pragma unroll
    for (int m = 0; m < 5; m++) v2[m] += a2[n*80 + c*5 + m] * u;
  }
  #pragma unroll
  for (int m = 0; m < 5; m++) h2_out[n*80 + d*5 + m] = v2[m];
}

// ---------------------------------------------------------------------------
// Readout fwd + bwd fused. Folds block-1's h0 update:
// h = h0_s1[n] + a0_b1[n] @ U0b1 (h0_s2 never materialized).
// Outputs g0 and ga0b1 (separate buffer, no aliasing). No scratch spill.
// ---------------------------------------------------------------------------
__global__ void __launch_bounds__(256, 1)
k_readout_bwd(const float* __restrict__ h0s1, const float* __restrict__ a0in,
              const float* __restrict__ W_read,
              const float* __restrict__ W1, const float* __restrict__ b1,
              const float* __restrict__ W2, const float* __restrict__ b2,
              const float* __restrict__ U0b1,
              float* __restrict__ g0, float* __restrict__ ga0,
              float* __restrict__ partials, int N)
{
  __shared__ float sWr[256], sW1[256], sU[256], sb1[16], sW2[16], sb2;
  __shared__ float swave[4];
  {
    int t = threadIdx.x;
    if (t < 256) { sWr[t] = W_read[t]; sW1[t] = W1[t]; sU[t] = U0b1[t]; }
    if (t < 16)  { sb1[t] = b1[t]; sW2[t] = W2[t]; }
    if (t == 0)  sb2 = b2[0];
  }
  __syncthreads();
  int n = blockIdx.x * blockDim.x + threadIdx.x;
  float site = 0.f;
  if (n < N) {
    float h[16], av[16], inv[16], dt[16], g0v[16];
    #pragma unroll
    for (int d = 0; d < 16; d++) av[d] = a0in[n*16 + d];
    #pragma unroll
    for (int d = 0; d < 16; d++) {
      float s = h0s1[n*16 + d];
      #pragma unroll
      for (int cc = 0; cc < 16; cc++) s += av[cc] * sU[cc*16 + d];
      h[d] = s;
    }
    #pragma unroll
    for (int j = 0; j < 16; j++) {
      float s = 0.f;
      #pragma unroll
      for (int d = 0; d < 16; d++) s += h[d] * sWr[d*16 + j];
      inv[j] = s;
    }
    site = sb2;
    #pragma unroll
    for (int c = 0; c < 16; c++) {
      float t = sb1[c];
      #pragma unroll
      for (int j = 0; j < 16; j++) t += inv[j] * sW1[j*16 + c];
      float sg = 1.f / (1.f + expf(-t));
      float w2v = sW2[c];
      site += t * sg * w2v;
      dt[c] = w2v * sg * (1.f + t * (1.f - sg));
    }
    float dinv[16];
    #pragma unroll
    for (int j = 0; j < 16; j++) {
      float s = 0.f;
      #pragma unroll
      for (int c = 0; c < 16; c++) s += dt[c] * sW1[j*16 + c];
      dinv[j] = s;
    }
    #pragma unroll
    for (int d = 0; d < 16; d++) {
      float s = 0.f;
      #pragma unroll
      for (int j = 0; j < 16; j++) s += dinv[j] * sWr[d*16 + j];
      g0v[d] = s;
      g0[n*16 + d] = s;
    }
    #pragma unroll
    for (int c = 0; c < 16; c++) {
      float s = 0.f;
      #pragma unroll
      for (int d = 0; d < 16; d++) s += g0v[d] * sU[c*16 + d];
      ga0[n*16 + c] = s;
    }
  }
  #pragma unroll
  for (int off = 32; off; off >>= 1) site += __shfl_down(site, off, 64);
  int wave = threadIdx.x >> 6;
  if ((threadIdx.x & 63) == 0) swave[wave] = site;
  __syncthreads();
  if (threadIdx.x == 0)
    partials[blockIdx.x] = swave[0] + swave[1] + swave[2] + swave[3];
}

// Sum per-block partials into energy (single tiny block).
__global__ void k_energy(const float* __restrict__ partials, int nb,
                         float* __restrict__ energy)
{
  int t = threadIdx.x;           // 128 threads (2 waves)
  float s = 0.f;
  for (int i = t; i < nb; i += 128) s += partials[i];
  #pragma unroll
  for (int off = 32; off; off >>= 1) s += __shfl_down(s, off, 64);
  __shared__ float sw[2];
  if ((t & 63) == 0) sw[t >> 6] = s;
  __syncthreads();
  if (t == 0) energy[0] = sw[0] + sw[1];
}

// ---------------------------------------------------------------------------
// ga = g @ U^T (full, for block 0 backward)
// ---------------------------------------------------------------------------
__global__ void k_ga(const float* __restrict__ g0, const float* __restrict__ g1,
                     const float* __restrict__ g2, const float* __restrict__ U,
                     float* __restrict__ ga0, float* __restrict__ ga1, float* __restrict__ ga2,
                     int N)
{
  int idx = blockIdx.x * blockDim.x + threadIdx.x;
  int n = idx >> 4, c = idx & 15;
  if (n >= N) return;
  const float* U0 = U;
  const float* U1 = U + 256;
  const float* U2 = U + 512;
  float s = 0.f;
  #pragma unroll
  for (int d = 0; d < 16; d++) s += g0[n*16 + d] * U0[c*16 + d];
  ga0[n*16 + c] = s;
  float v1[3] = {0.f, 0.f, 0.f};
  #pragma unroll
  for (int d = 0; d < 16; d++) {
    float u = U1[c*16 + d];
    #pragma unroll
    for (int m = 0; m < 3; m++) v1[m] += g1[n*48 + d*3 + m] * u;
  }
  #pragma unroll
  for (int m = 0; m < 3; m++) ga1[n*48 + c*3 + m] = v1[m];
  float v2[5] = {0.f, 0.f, 0.f, 0.f, 0.f};
  #pragma unroll
  for (int d = 0; d < 16; d++) {
    float u = U2[c*16 + d];
    #pragma unroll
    for (int m = 0; m < 5; m++) v2[m] += g2[n*80 + d*5 + m] * u;
  }
  #pragma unroll
  for (int m = 0; m < 5; m++) ga2[n*80 + c*5 + m] = v2[m];
}

// ---------------------------------------------------------------------------
// Backward block 1, col-centric — wave per node. Streams uC + precomputed
// rdC (rad+draddr, 4xfloat4/edge) — no per-edge recurrence.
// ---------------------------------------------------------------------------
__global__ void k_bwd_b1_col(const float* __restrict__ Wr, const float* __restrict__ br,
                             const float* __restrict__ h0_in, const float* __restrict__ h1_in,
                             const float* __restrict__ h2_in,
                             const float* __restrict__ ga0,
                             const float4* __restrict__ uC, const float4* __restrict__ rdC,
                             const int* __restrict__ rowC,
                             const int* __restrict__ start_col, const int* __restrict__ deg_col,
                             float* __restrict__ g0, float* __restrict__ g1, float* __restrict__ g2,
                             float* __restrict__ dv_col, int N)
{
  int n = (blockIdx.x * blockDim.x + threadIdx.x) >> 6;
  int lane = threadIdx.x & 63;
  int g = lane >> 4, c = lane & 15;
  if (n >= N) return;
  float wr0[8], wr3[8], wr4[8];
  #pragma unroll
  for (int k = 0; k < 8; k++) {
    wr0[k] = Wr[k*80 + c];
    wr3[k] = Wr[k*80 + 48 + c];
    wr4[k] = Wr[k*80 + 64 + c];
  }
  float b0v = br[c], b3v = br[48 + c], b4v = br[64 + c];

  float h0c = h0_in[n*16 + c];
  float h1c[3], h2c[5];
  #pragma unroll
  for (int m = 0; m < 3; m++) h1c[m] = h1_in[n*48 + c*3 + m];
  #pragma unroll
  for (int m = 0; m < 5; m++) h2c[m] = h2_in[n*80 + c*5 + m];

  float accg0 = 0.f, accg1[3] = {0.f,0.f,0.f}, accg2[5] = {0.f,0.f,0.f,0.f,0.f};

  int i0 = start_col[n] + g, i1 = start_col[n] + deg_col[n];
  float4 Un = {0,0,0,0}, R0n = {0,0,0,0}, R1n = {0,0,0,0}, R2n = {0,0,0,0}, R3n = {0,0,0,0};
  float dm0n = 0.f;
  if (i0 < i1) {
    Un = uC[i0];
    R0n = rdC[i0*4+0]; R1n = rdC[i0*4+1]; R2n = rdC[i0*4+2]; R3n = rdC[i0*4+3];
    dm0n = ga0[rowC[i0]*16 + c];
  }
  for (int i = i0; i < i1; i += 4) {
    float4 U = Un, R0 = R0n, R1 = R1n, R2 = R2n, R3 = R3n;
    float dm0 = dm0n;
    if (i+4 < i1) {
      Un = uC[i+4];
      R0n = rdC[(i+4)*4+0]; R1n = rdC[(i+4)*4+1]; R2n = rdC[(i+4)*4+2]; R3n = rdC[(i+4)*4+3];
      dm0n = ga0[rowC[i+4]*16 + c];
    }
    float rad[8]    = {R0.x,R0.y,R0.z,R0.w,R1.x,R1.y,R1.z,R1.w};
    float draddr[8] = {R2.x,R2.y,R2.z,R2.w,R3.x,R3.y,R3.z,R3.w};
    float ux = U.x, uy = U.y, uz = U.z, inv_r = U.w;
    float sh1[3], sh2[5];
    sh_from_u(ux, uy, uz, sh1, sh2);

    float w0 = b0v, w3 = b3v, w4 = b4v;
    #pragma unroll
    for (int k = 0; k < 8; k++) {
      w0 += rad[k]*wr0[k]; w3 += rad[k]*wr3[k]; w4 += rad[k]*wr4[k];
    }

    float S1 = 0.f, S2 = 0.f;
    #pragma unroll
    for (int m = 0; m < 3; m++) S1 += h1c[m]*sh1[m];
    #pragma unroll
    for (int m = 0; m < 5; m++) S2 += h2c[m]*sh2[m];

    float dw0 = dm0 * h0c;
    float dw3 = dm0 * S1;
    float dw4 = dm0 * S2;
    float t3 = dm0 * w3, t4 = dm0 * w4;

    accg0 += dm0 * w0;
    #pragma unroll
    for (int m = 0; m < 3; m++) accg1[m] += t3 * sh1[m];
    #pragma unroll
    for (int m = 0; m < 5; m++) accg2[m] += t4 * sh2[m];

    float q1x = t3*h1c[0], q1y = t3*h1c[1], q1z = t3*h1c[2];
    float q0 = t4*h2c[0], q1 = t4*h2c[1], q2 = t4*h2c[2], q3 = t4*h2c[3], q4 = t4*h2c[4];
    float gr = 0.f;
    #pragma unroll
    for (int k = 0; k < 8; k++)
      gr += (dw0*wr0[k] + dw3*wr3[k] + dw4*wr4[k]) * draddr[k];
    float gux = SQRT3f*q1x + SQRT15f*(uy*q0 + uz*q3 + ux*q4);
    float guy = SQRT3f*q1y + SQRT15f*(ux*q0 + uz*q1 - uy*q4);
    float guz = SQRT3f*q1z + SQRT15f*uy*q1 + 3.f*SQRT5f*uz*q2 + SQRT15f*ux*q3;

    gr  = grp16_sum(gr);
    gux = grp16_sum(gux);
    guy = grp16_sum(guy);
    guz = grp16_sum(guz);

    if (c == 0) {
      float gdotu = gux*ux + guy*uy + guz*uz;
      dv_col[i*3+0] = gr*ux + (gux - gdotu*ux)*inv_r;
      dv_col[i*3+1] = gr*uy + (guy - gdotu*uy)*inv_r;
      dv_col[i*3+2] = gr*uz + (guz - gdotu*uz)*inv_r;
    }
  }
  accg0 = xgrp_sum(accg0);
  #pragma unroll
  for (int m = 0; m < 3; m++) accg1[m] = xgrp_sum(accg1[m]);
  #pragma unroll
  for (int m = 0; m < 5; m++) accg2[m] = xgrp_sum(accg2[m]);
  if (g == 0) {
    g0[n*16 + c] += accg0;
    #pragma unroll
    for (int m = 0; m < 3; m++) g1[n*48 + c*3 + m] = accg1[m];
    #pragma unroll
    for (int m = 0; m < 5; m++) g2[n*80 + c*5 + m] = accg2[m];
  }
}

// ---------------------------------------------------------------------------
// Backward block 0, row-centric — wave per node; dv written to dv_row stream.
// ---------------------------------------------------------------------------
__global__ void k_bwd_b0_row(const float* __restrict__ Wr, const float* __restrict__ br,
                             const float* __restrict__ h0_in,
                             const float* __restrict__ ga0, const float* __restrict__ ga1,
                             const float* __restrict__ ga2,
                             const float4* __restrict__ uR, const float2* __restrict__ scR,
                             const int* __restrict__ colR,
                             const int* __restrict__ start_row, const int* __restrict__ deg_row,
                             float* __restrict__ dv_row, int N)
{
  int n = (blockIdx.x * blockDim.x + threadIdx.x) >> 6;
  int lane = threadIdx.x & 63;
  int g = lane >> 4, c = lane & 15;
  if (n >= N) return;
  float wr0[8], wr1[8], wr2[8];
  #pragma unroll
  for (int k = 0; k < 8; k++) {
    wr0[k] = Wr[k*80 + c];
    wr1[k] = Wr[k*80 + 16 + c];
    wr2[k] = Wr[k*80 + 32 + c];
  }
  float b1v = br[16 + c], b2v = br[32 + c];

  float dm0 = ga0[n*16 + c];
  float dm1[3], dm2[5];
  #pragma unroll
  for (int m = 0; m < 3; m++) dm1[m] = ga1[n*48 + c*3 + m];
  #pragma unroll
  for (int m = 0; m < 5; m++) dm2[m] = ga2[n*80 + c*5 + m];

  int i0 = start_row[n] + g, i1 = start_row[n] + deg_row[n];
  float4 Un = {0,0,0,0}; float2 SCn = {0,0};
  float h0n = 0.f;
  if (i0 < i1) {
    Un = uR[i0]; SCn = scR[i0];
    h0n = h0_in[colR[i0]*16 + c];
  }
  for (int i = i0; i < i1; i += 4) {
    float4 U = Un; float2 SC = SCn;
    float h0c = h0n;
    if (i+4 < i1) {
      Un = uR[i+4]; SCn = scR[i+4];
      h0n = h0_in[colR[i+4]*16 + c];
    }
    float rad[8], draddr[8];
    rad_drad_from_sc(SC.x, SC.y, U.w, rad, draddr);
    float ux = U.x, uy = U.y, uz = U.z, inv_r = U.w;
    float sh1[3], sh2[5];
    sh_from_u(ux, uy, uz, sh1, sh2);

    float w1 = b1v, w2v = b2v;
    #pragma unroll
    for (int k = 0; k < 8; k++) { w1 += rad[k]*wr1[k]; w2v += rad[k]*wr2[k]; }

    float T1 = 0.f, T2 = 0.f;
    #pragma unroll
    for (int m = 0; m < 3; m++) T1 += dm1[m]*sh1[m];
    #pragma unroll
    for (int m = 0; m < 5; m++) T2 += dm2[m]*sh2[m];

    float dw0 = dm0 * h0c;
    float dw1 = h0c * T1;
    float dw2 = h0c * T2;

    float w1h = w1*h0c, w2h = w2v*h0c;
    float q1x = dm1[0]*w1h, q1y = dm1[1]*w1h, q1z = dm1[2]*w1h;
    float q0 = dm2[0]*w2h, q1 = dm2[1]*w2h, q2 = dm2[2]*w2h, q3 = dm2[3]*w2h, q4 = dm2[4]*w2h;

    float gr = 0.f;
    #pragma unroll
    for (int k = 0; k < 8; k++)
      gr += (dw0*wr0[k] + dw1*wr1[k] + dw2*wr2[k]) * draddr[k];
    float gux = SQRT3f*q1x + SQRT15f*(uy*q0 + uz*q3 + ux*q4);
    float guy = SQRT3f*q1y + SQRT15f*(ux*q0 + uz*q1 - uy*q4);
    float guz = SQRT3f*q1z + SQRT15f*uy*q1 + 3.f*SQRT5f*uz*q2 + SQRT15f*ux*q3;

    gr  = grp16_sum(gr);
    gux = grp16_sum(gux);
    guy = grp16_sum(guy);
    guz = grp16_sum(guz);

    if (c == 0) {
      float gdotu = gux*ux + guy*uy + guz*uz;
      dv_row[i*3+0] = gr*ux + (gux - gdotu*ux)*inv_r;
      dv_row[i*3+1] = gr*uy + (guy - gdotu*uy)*inv_r;
      dv_row[i*3+2] = gr*uz + (guz - gdotu*uz)*inv_r;
    }
  }
}

// ---------------------------------------------------------------------------
// Force assembly: dv_e = dv_col[colpos(e)] + dv_row[rowpos(e)].
// ---------------------------------------------------------------------------
__global__ void k_force(const int* __restrict__ start_row, const int* __restrict__ deg_row,
                        const int* __restrict__ cposR,
                        const int* __restrict__ start_col, const int* __restrict__ deg_col,
                        const int* __restrict__ rposC,
                        const float* __restrict__ dv_col, const float* __restrict__ dv_row,
                        float* __restrict__ force, int N)
{
  int n = blockIdx.x * blockDim.x + threadIdx.x;
  if (n >= N) return;
  float fx = 0.f, fy = 0.f, fz = 0.f;
  int c0 = start_col[n], c1 = c0 + deg_col[n];
  for (int i = c0; i < c1; i++) {
    int rp = rposC[i];
    fx += dv_col[i*3+0] + dv_row[rp*3+0];
    fy += dv_col[i*3+1] + dv_row[rp*3+1];
    fz += dv_col[i*3+2] + dv_row[rp*3+2];
  }
  int r0 = start_row[n], r1 = r0 + deg_row[n];
  for (int i = r0; i < r1; i++) {
    int cp = cposR[i];
    fx -= dv_row[i*3+0] + dv_col[cp*3+0];
    fy -= dv_row[i*3+1] + dv_col[cp*3+1];
    fz -= dv_row[i*3+2] + dv_col[cp*3+2];
  }
  force[n*3+0] = fx; force[n*3+1] = fy; force[n*3+2] = fz;
}

// ---------------------------------------------------------------------------
extern "C" void kernel_launch(void* const* d_in, const int* in_sizes, int n_in,
                              void* d_out, int out_size, void* d_ws, size_t ws_size,
                              hipStream_t stream)
{
  const float* pos    = (const float*)d_in[0];
  const int*   z      = (const int*)  d_in[1];
  const int*   ei     = (const int*)  d_in[2];
  const float* emb    = (const float*)d_in[3];
  const float* W_init = (const float*)d_in[4];
  const float* Wr     = (const float*)d_in[5];   // (2, 8, 80)
  const float* br     = (const float*)d_in[6];   // (2, 80)
  const float* W_out  = (const float*)d_in[7];   // (2, 3, 16, 16)
  const float* W_read = (const float*)d_in[8];
  const float* W1     = (const float*)d_in[9];
  const float* b1     = (const float*)d_in[10];
  const float* W2     = (const float*)d_in[11];
  const float* b2     = (const float*)d_in[12];

  const int N = in_sizes[0] / 3;
  const int E = in_sizes[2] / 2;

  const int BLK = 256;
  const int NPB = BLK / 64;  // nodes per block (wave-per-node kernels)
  const int NB_READOUT = cdiv(N, BLK);

  float* f = (float*)d_ws;
  float4* uR  = (float4*)f; f += (size_t)E*4;
  float4* uC  = (float4*)f; f += (size_t)E*4;
  float2* scR = (float2*)f; f += (size_t)E*2;
  float4* rdC = (float4*)f; f += (size_t)E*16;   // precomputed rad+draddr, col order
  float* h0_s0 = f; f += (size_t)N*16;
  float* h0_s1 = f; f += (size_t)N*16;
  float* h1_s1 = f; f += (size_t)N*48;
  float* h2_s1 = f; f += (size_t)N*80;
  float* a0    = f; f += (size_t)N*16;   // block-0 agg, then block-1 agg, then ga0_b0
  float* a1    = f; f += (size_t)N*48;   //                                 ga1_b0
  float* a2    = f; f += (size_t)N*80;   //                                 ga2_b0
  float* ga0b1 = f; f += (size_t)N*16;   // readout's ga0 (dE/da0 block 1)
  float* g0    = f; f += (size_t)N*16;
  float* g1    = f; f += (size_t)N*48;
  float* g2    = f; f += (size_t)N*80;
  float* dv_c  = f; f += (size_t)E*3;    // dv from bwd b1, col order
  float* dv_r  = f; f += (size_t)E*3;    // dv from bwd b0, row order
  float* partials = f; f += (size_t)NB_READOUT;
  int* ip = (int*)f;
  int* cursors   = ip; ip += 2;          // cursors+deg contiguous -> one memset
  int* deg_row   = ip; ip += N;
  int* deg_col   = ip; ip += N;
  int* start_row = ip; ip += N;
  int* start_col = ip; ip += N;
  int* cur_row   = ip; ip += N;
  int* cur_col   = ip; ip += N;
  int* colR      = ip; ip += E;
  int* cposR     = ip; ip += E;
  int* rowC      = ip; ip += E;
  int* rposC     = ip; ip += E;

  float* out    = (float*)d_out;
  float* energy = out;
  float* force  = out + 1;

  (void)hipMemsetAsync(cursors, 0, (size_t)(2 + 2*N) * sizeof(int), stream);

  // ---- CSR build (scan-free) + geometry (col order carries rad+draddr) ----
  k_hist<<<cdiv(E, BLK), BLK, 0, stream>>>(ei, E, deg_row, deg_col);
  k_alloc<<<cdiv(N, BLK), BLK, 0, stream>>>(deg_row, deg_col, start_row, cur_row,
                                            start_col, cur_col, cursors, N);
  k_scatter_geom<<<cdiv(E, BLK), BLK, 0, stream>>>(pos, ei, E, cur_row, cur_col,
                                                   uR, scR, uC, rdC,
                                                   colR, cposR, rowC, rposC);

  k_node_init<<<cdiv(N, BLK), BLK, 0, stream>>>(emb, z, W_init, h0_s0, N);

  // ---- forward block 0 ----
  k_fwd_b0<<<cdiv(N, NPB), BLK, 0, stream>>>(Wr, br, h0_s0, uR, scR, colR,
                                             start_row, deg_row, a0, a1, a2, N);
  k_node_update<<<cdiv(N*16, BLK), BLK, 0, stream>>>(h0_s0, a0, a1, a2,
                                                     W_out, h0_s1, h1_s1, h2_s1, N);

  // ---- forward block 1 (h0_s2 folded into readout) ----
  k_fwd_b1<<<cdiv(N, NPB), BLK, 0, stream>>>(Wr + 640, br + 80,
                                             h0_s1, h1_s1, h2_s1, uR, scR, colR,
                                             start_row, deg_row, a0, N);

  // ---- readout fwd + bwd (includes block-1 h0 update; emits g0, ga0b1) ----
  k_readout_bwd<<<NB_READOUT, BLK, 0, stream>>>(h0_s1, a0, W_read, W1, b1, W2, b2,
                                                W_out + 768, g0, ga0b1, partials, N);
  k_energy<<<1, 128, 0, stream>>>(partials, NB_READOUT, energy);

  // ---- backward block 1 ----
  k_bwd_b1_col<<<cdiv(N, NPB), BLK, 0, stream>>>(Wr + 640, br + 80,
                                                 h0_s1, h1_s1, h2_s1, ga0b1,
                                                 uC, rdC, rowC, start_col, deg_col,
                                                 g0, g1, g2, dv_c, N);

  // ---- backward block 0 ----
  k_ga<<<cdiv(N*16, BLK), BLK, 0, stream>>>(g0, g1, g2, W_out, a0, a1, a2, N);
  k_bwd_b0_row<<<cdiv(N, NPB), BLK, 0, stream>>>(Wr, br, h0_s0,
                                                 a0, a1, a2, uR, scR, colR,
                                                 start_row, deg_row, dv_r, N);

  // ---- force assembly ----
  k_force<<<cdiv(N, BLK), BLK, 0, stream>>>(start_row, deg_row, cposR,
                                            start_col, deg_col, rposC,
                                            dv_c, dv_r, force, N);
}

// Round 17
// 494.622 us; speedup vs baseline: 1.0209x; 1.0209x over previous
//
#include <hip/hip_runtime.h>
#include <math.h>

#ifndef M_PI
#define M_PI 3.14159265358979323846
#endif

static inline int cdiv(int a, int b){ return (a + b - 1) / b; }

#define SQRT3f  1.7320508075688772f
#define SQRT5f  2.23606797749979f
#define SQRT15f 3.872983346207417f
#define KRADf   0.6324555320336759f      /* sqrt(2/R_MAX), R_MAX=5 */
#define PI5f    0.6283185307179586f      /* pi/5 */

// sum over the 16-lane channel group (within-group, xor 1..8)
__device__ __forceinline__ float grp16_sum(float v){
  v += __shfl_xor(v, 1, 64);
  v += __shfl_xor(v, 2, 64);
  v += __shfl_xor(v, 4, 64);
  v += __shfl_xor(v, 8, 64);
  return v;
}
// sum across the 4 groups of a wave (same channel lane in each group)
__device__ __forceinline__ float xgrp_sum(float v){
  v += __shfl_xor(v, 16, 64);
  v += __shfl_xor(v, 32, 64);
  return v;
}

// sh from unit vector (8 ops)
__device__ __forceinline__ void sh_from_u(float ux, float uy, float uz,
                                          float* sh1, float* sh2)
{
  sh1[0] = SQRT3f*ux; sh1[1] = SQRT3f*uy; sh1[2] = SQRT3f*uz;
  sh2[0] = SQRT15f*ux*uy;
  sh2[1] = SQRT15f*uy*uz;
  sh2[2] = 0.5f*SQRT5f*(3.f*uz*uz - 1.f);
  sh2[3] = SQRT15f*ux*uz;
  sh2[4] = 0.5f*SQRT15f*(ux*ux - uy*uy);
}

// Chebyshev recurrences from (s1,c1)=sincos(pi*r/5): rad only (fwd)
__device__ __forceinline__ void rad_from_sc(float s1, float c1, float inv_r, float* rad)
{
  float tc = 2.f * c1;
  float sprev = 0.f, s = s1;
  float Ki = KRADf * inv_r;
  #pragma unroll
  for (int k = 0; k < 8; k++) {
    rad[k] = Ki * s;
    float sn = tc*s - sprev; sprev = s; s = sn;
  }
}
// rad + draddr (bwd). NOTE (r16 post-mortem): precomputing this into a
// streamed buffer regressed — the wider prefetch state spilled to scratch
// (+100 MB HBM traffic). Recompute is cheaper than registers here.
__device__ __forceinline__ void rad_drad_from_sc(float s1, float c1, float inv_r,
                                                 float* rad, float* draddr)
{
  float tc = 2.f * c1;
  float sprev = 0.f, s = s1, cprev = 1.f, cc = c1;
  float Ki = KRADf * inv_r;
  const float KPI5 = KRADf * PI5f;
  #pragma unroll
  for (int k = 0; k < 8; k++) {
    rad[k] = Ki * s;
    draddr[k] = (KPI5 * (float)(k+1) * cc - rad[k]) * inv_r;
    float sn = tc*s - sprev; sprev = s; s = sn;
    float cn = tc*cc - cprev; cprev = cc; cc = cn;
  }
}

// ---------------------------------------------------------------------------
// Degree histogram (E-parallel)
// ---------------------------------------------------------------------------
__global__ void k_hist(const int* __restrict__ ei, int E,
                       int* __restrict__ deg_row, int* __restrict__ deg_col)
{
  int e = blockIdx.x * blockDim.x + threadIdx.x;
  if (e >= E) return;
  atomicAdd(&deg_row[ei[e]], 1);
  atomicAdd(&deg_col[ei[E + e]], 1);
}

// ---------------------------------------------------------------------------
// Scan-free segment allocation: wave-aggregated atomicAdd on global cursors.
// ---------------------------------------------------------------------------
__global__ void k_alloc(const int* __restrict__ deg_row, const int* __restrict__ deg_col,
                        int* __restrict__ start_row, int* __restrict__ cur_row,
                        int* __restrict__ start_col, int* __restrict__ cur_col,
                        int* __restrict__ cursors, int N)
{
  int idx = blockIdx.x * blockDim.x + threadIdx.x;
  int lane = threadIdx.x & 63;
  #pragma unroll
  for (int which = 0; which < 2; which++) {
    const int* deg = which ? deg_col : deg_row;
    int* start = which ? start_col : start_row;
    int* cur   = which ? cur_col   : cur_row;
    int v = (idx < N) ? deg[idx] : 0;
    int incl = v;
    #pragma unroll
    for (int d = 1; d < 64; d <<= 1) {
      int y = __shfl_up(incl, d, 64);
      if (lane >= d) incl += y;
    }
    int wtot = __shfl(incl, 63, 64);
    int base = 0;
    if (lane == 63) base = atomicAdd(&cursors[which], wtot);
    base = __shfl(base, 63, 64);
    if (idx < N) { int st = base + incl - v; start[idx] = st; cur[idx] = st; }
  }
}

// ---------------------------------------------------------------------------
// Scatter + compact geometry in BOTH CSR orders.
// ---------------------------------------------------------------------------
__global__ void k_scatter_geom(const float* __restrict__ pos, const int* __restrict__ ei, int E,
                               int* __restrict__ cur_row, int* __restrict__ cur_col,
                               float4* __restrict__ uR, float2* __restrict__ scR,
                               float4* __restrict__ uC, float2* __restrict__ scC,
                               int* __restrict__ colR, int* __restrict__ cposR,
                               int* __restrict__ rowC, int* __restrict__ rposC)
{
  int e = blockIdx.x * blockDim.x + threadIdx.x;
  if (e >= E) return;
  int row = ei[e], col = ei[E + e];
  int pr = atomicAdd(&cur_row[row], 1);
  int pc = atomicAdd(&cur_col[col], 1);
  colR[pr] = col; cposR[pr] = pc;
  rowC[pc] = row; rposC[pc] = pr;

  float px = pos[row*3+0] - pos[col*3+0];
  float py = pos[row*3+1] - pos[col*3+1];
  float pz = pos[row*3+2] - pos[col*3+2];
  float r2 = px*px + py*py + pz*pz + 1e-12f;
  float r = sqrtf(r2);
  float inv_r = 1.0f / r;
  float ux = px*inv_r, uy = py*inv_r, uz = pz*inv_r;
  float s1, c1;
  sincosf(r * PI5f, &s1, &c1);
  float4 u4 = make_float4(ux, uy, uz, inv_r);
  float2 sc = make_float2(s1, c1);
  uR[pr] = u4; scR[pr] = sc;
  uC[pc] = u4; scC[pc] = sc;
}

// ---------------------------------------------------------------------------
// h0_init[n,:] = emb[z[n],:] @ W_init
// ---------------------------------------------------------------------------
__global__ void k_node_init(const float* __restrict__ emb, const int* __restrict__ z,
                            const float* __restrict__ W_init, float* __restrict__ h0, int N)
{
  __shared__ float sW[256];
  if (threadIdx.x < 256) sW[threadIdx.x] = W_init[threadIdx.x];
  __syncthreads();
  int n = blockIdx.x * blockDim.x + threadIdx.x;
  if (n >= N) return;
  const float* e = emb + z[n]*16;
  float ev[16];
  #pragma unroll
  for (int k = 0; k < 16; k++) ev[k] = e[k];
  #pragma unroll
  for (int c = 0; c < 16; c++) {
    float s = 0.f;
    #pragma unroll
    for (int k = 0; k < 16; k++) s += ev[k] * sW[k*16+c];
    h0[n*16+c] = s;
  }
}

// ---------------------------------------------------------------------------
// Forward block 0 — wave per node (4 groups x 16 channels, stride-4 edges).
// ---------------------------------------------------------------------------
__global__ void k_fwd_b0(const float* __restrict__ Wr, const float* __restrict__ br,
                         const float* __restrict__ h0_in,
                         const float4* __restrict__ uR, const float2* __restrict__ scR,
                         const int* __restrict__ colR,
                         const int* __restrict__ start_row, const int* __restrict__ deg_row,
                         float* __restrict__ a0, float* __restrict__ a1, float* __restrict__ a2,
                         int N)
{
  int n = (blockIdx.x * blockDim.x + threadIdx.x) >> 6;
  int lane = threadIdx.x & 63;
  int g = lane >> 4, c = lane & 15;
  if (n >= N) return;
  float wr0[8], wr1[8], wr2[8];
  #pragma unroll
  for (int k = 0; k < 8; k++) {
    wr0[k] = Wr[k*80 + c];
    wr1[k] = Wr[k*80 + 16 + c];
    wr2[k] = Wr[k*80 + 32 + c];
  }
  float b0v = br[c], b1v = br[16 + c], b2v = br[32 + c];

  float acc0 = 0.f, acc1[3] = {0.f,0.f,0.f}, acc2[5] = {0.f,0.f,0.f,0.f,0.f};

  int i0 = start_row[n] + g, i1 = start_row[n] + deg_row[n];
  float4 Un = {0,0,0,0}; float2 SCn = {0,0};
  float h0n = 0.f;
  if (i0 < i1) {
    Un = uR[i0]; SCn = scR[i0];
    h0n = h0_in[colR[i0]*16 + c];
  }
  for (int i = i0; i < i1; i += 4) {
    float4 U = Un; float2 SC = SCn;
    float h0c = h0n;
    if (i+4 < i1) {
      Un = uR[i+4]; SCn = scR[i+4];
      h0n = h0_in[colR[i+4]*16 + c];
    }
    float rad[8];
    rad_from_sc(SC.x, SC.y, U.w, rad);
    float sh1[3], sh2[5];
    sh_from_u(U.x, U.y, U.z, sh1, sh2);
    float w0 = b0v, w1 = b1v, w2 = b2v;
    #pragma unroll
    for (int k = 0; k < 8; k++) {
      w0 += rad[k]*wr0[k]; w1 += rad[k]*wr1[k]; w2 += rad[k]*wr2[k];
    }
    acc0 += w0*h0c;
    float wh1 = w1*h0c, wh2 = w2*h0c;
    #pragma unroll
    for (int m = 0; m < 3; m++) acc1[m] += wh1*sh1[m];
    #pragma unroll
    for (int m = 0; m < 5; m++) acc2[m] += wh2*sh2[m];
  }
  acc0 = xgrp_sum(acc0);
  #pragma unroll
  for (int m = 0; m < 3; m++) acc1[m] = xgrp_sum(acc1[m]);
  #pragma unroll
  for (int m = 0; m < 5; m++) acc2[m] = xgrp_sum(acc2[m]);
  if (g == 0) {
    a0[n*16 + c] = acc0;
    #pragma unroll
    for (int m = 0; m < 3; m++) a1[n*48 + c*3 + m] = acc1[m];
    #pragma unroll
    for (int m = 0; m < 5; m++) a2[n*80 + c*5 + m] = acc2[m];
  }
}

// ---------------------------------------------------------------------------
// Forward block 1 (last) — wave per node.
// ---------------------------------------------------------------------------
__global__ void k_fwd_b1(const float* __restrict__ Wr, const float* __restrict__ br,
                         const float* __restrict__ h0_in, const float* __restrict__ h1_in,
                         const float* __restrict__ h2_in,
                         const float4* __restrict__ uR, const float2* __restrict__ scR,
                         const int* __restrict__ colR,
                         const int* __restrict__ start_row, const int* __restrict__ deg_row,
                         float* __restrict__ a0, int N)
{
  int n = (blockIdx.x * blockDim.x + threadIdx.x) >> 6;
  int lane = threadIdx.x & 63;
  int g = lane >> 4, c = lane & 15;
  if (n >= N) return;
  float wr0[8], wr3[8], wr4[8];
  #pragma unroll
  for (int k = 0; k < 8; k++) {
    wr0[k] = Wr[k*80 + c];
    wr3[k] = Wr[k*80 + 48 + c];
    wr4[k] = Wr[k*80 + 64 + c];
  }
  float b0v = br[c], b3v = br[48 + c], b4v = br[64 + c];

  float acc0 = 0.f;
  int i0 = start_row[n] + g, i1 = start_row[n] + deg_row[n];
  float4 Un = {0,0,0,0}; float2 SCn = {0,0};
  float h0n = 0.f, h1n[3] = {0,0,0}, h2n[5] = {0,0,0,0,0};
  if (i0 < i1) {
    int col = colR[i0];
    Un = uR[i0]; SCn = scR[i0];
    h0n = h0_in[col*16 + c];
    #pragma unroll
    for (int m = 0; m < 3; m++) h1n[m] = h1_in[col*48 + c*3 + m];
    #pragma unroll
    for (int m = 0; m < 5; m++) h2n[m] = h2_in[col*80 + c*5 + m];
  }
  for (int i = i0; i < i1; i += 4) {
    float4 U = Un; float2 SC = SCn;
    float h0c = h0n;
    float h1c[3], h2c[5];
    #pragma unroll
    for (int m = 0; m < 3; m++) h1c[m] = h1n[m];
    #pragma unroll
    for (int m = 0; m < 5; m++) h2c[m] = h2n[m];
    if (i+4 < i1) {
      int col = colR[i+4];
      Un = uR[i+4]; SCn = scR[i+4];
      h0n = h0_in[col*16 + c];
      #pragma unroll
      for (int m = 0; m < 3; m++) h1n[m] = h1_in[col*48 + c*3 + m];
      #pragma unroll
      for (int m = 0; m < 5; m++) h2n[m] = h2_in[col*80 + c*5 + m];
    }
    float rad[8];
    rad_from_sc(SC.x, SC.y, U.w, rad);
    float sh1[3], sh2[5];
    sh_from_u(U.x, U.y, U.z, sh1, sh2);
    float w0 = b0v, w3 = b3v, w4 = b4v;
    #pragma unroll
    for (int k = 0; k < 8; k++) {
      w0 += rad[k]*wr0[k]; w3 += rad[k]*wr3[k]; w4 += rad[k]*wr4[k];
    }
    float S1 = 0.f, S2 = 0.f;
    #pragma unroll
    for (int m = 0; m < 3; m++) S1 += h1c[m]*sh1[m];
    #pragma unroll
    for (int m = 0; m < 5; m++) S2 += h2c[m]*sh2[m];
    acc0 += w0*h0c + w3*S1 + w4*S2;
  }
  acc0 = xgrp_sum(acc0);
  if (g == 0) a0[n*16 + c] = acc0;
}

// ---------------------------------------------------------------------------
// Node update (block 0 only): h_out = h_in + a @ U
// ---------------------------------------------------------------------------
__global__ void k_node_update(const float* __restrict__ h0_in,
                              const float* __restrict__ a0, const float* __restrict__ a1,
                              const float* __restrict__ a2,
                              const float* __restrict__ U,
                              float* __restrict__ h0_out, float* __restrict__ h1_out,
                              float* __restrict__ h2_out, int N)
{
  int idx = blockIdx.x * blockDim.x + threadIdx.x;
  int n = idx >> 4, d = idx & 15;
  if (n >= N) return;
  const float* U0 = U;
  const float* U1 = U + 256;
  const float* U2 = U + 512;
  float s = h0_in[n*16 + d];
  #pragma unroll
  for (int c = 0; c < 16; c++) s += a0[n*16 + c] * U0[c*16 + d];
  h0_out[n*16 + d] = s;
  float v1[3] = {0.f, 0.f, 0.f};
  #pragma unroll
  for (int c = 0; c < 16; c++) {
    float u = U1[c*16 + d];
    #pragma unroll
    for (int m = 0; m < 3; m++) v1[m] += a1[n*48 + c*3 + m] * u;
  }
  #pragma unroll
  for (int m = 0; m < 3; m++) h1_out[n*48 + d*3 + m] = v1[m];
  float v2[5] = {0.f, 0.f, 0.f, 0.f, 0.f};
  #pragma unroll
  for (int c = 0; c < 16; c++) {
    float u = U2[c*16 + d];
    #pragma unroll
    for (int m = 0; m < 5; m++) v2[m] += a2[n*80 + c*5 + m] * u;
  }
  #pragma unroll
  for (int m = 0; m < 5; m++) h2_out[n*80 + d*5 + m] = v2[m];
}

// ---------------------------------------------------------------------------
// Readout fwd + bwd fused. Folds block-1's h0 update:
// h = h0_s1[n] + a0_b1[n] @ U0b1 (h0_s2 never materialized).
// Outputs g0 and ga0b1 (separate buffer, no aliasing). No scratch spill.
// ---------------------------------------------------------------------------
__global__ void __launch_bounds__(256, 1)
k_readout_bwd(const float* __restrict__ h0s1, const float* __restrict__ a0in,
              const float* __restrict__ W_read,
              const float* __restrict__ W1, const float* __restrict__ b1,
              const float* __restrict__ W2, const float* __restrict__ b2,
              const float* __restrict__ U0b1,
              float* __restrict__ g0, float* __restrict__ ga0,
              float* __restrict__ partials, int N)
{
  __shared__ float sWr[256], sW1[256], sU[256], sb1[16], sW2[16], sb2;
  __shared__ float swave[4];
  {
    int t = threadIdx.x;
    if (t < 256) { sWr[t] = W_read[t]; sW1[t] = W1[t]; sU[t] = U0b1[t]; }
    if (t < 16)  { sb1[t] = b1[t]; sW2[t] = W2[t]; }
    if (t == 0)  sb2 = b2[0];
  }
  __syncthreads();
  int n = blockIdx.x * blockDim.x + threadIdx.x;
  float site = 0.f;
  if (n < N) {
    float h[16], av[16], inv[16], dt[16], g0v[16];
    #pragma unroll
    for (int d = 0; d < 16; d++) av[d] = a0in[n*16 + d];
    #pragma unroll
    for (int d = 0; d < 16; d++) {
      float s = h0s1[n*16 + d];
      #pragma unroll
      for (int cc = 0; cc < 16; cc++) s += av[cc] * sU[cc*16 + d];
      h[d] = s;
    }
    #pragma unroll
    for (int j = 0; j < 16; j++) {
      float s = 0.f;
      #pragma unroll
      for (int d = 0; d < 16; d++) s += h[d] * sWr[d*16 + j];
      inv[j] = s;
    }
    site = sb2;
    #pragma unroll
    for (int c = 0; c < 16; c++) {
      float t = sb1[c];
      #pragma unroll
      for (int j = 0; j < 16; j++) t += inv[j] * sW1[j*16 + c];
      float sg = 1.f / (1.f + expf(-t));
      float w2v = sW2[c];
      site += t * sg * w2v;
      dt[c] = w2v * sg * (1.f + t * (1.f - sg));
    }
    float dinv[16];
    #pragma unroll
    for (int j = 0; j < 16; j++) {
      float s = 0.f;
      #pragma unroll
      for (int c = 0; c < 16; c++) s += dt[c] * sW1[j*16 + c];
      dinv[j] = s;
    }
    #pragma unroll
    for (int d = 0; d < 16; d++) {
      float s = 0.f;
      #pragma unroll
      for (int j = 0; j < 16; j++) s += dinv[j] * sWr[d*16 + j];
      g0v[d] = s;
      g0[n*16 + d] = s;
    }
    #pragma unroll
    for (int c = 0; c < 16; c++) {
      float s = 0.f;
      #pragma unroll
      for (int d = 0; d < 16; d++) s += g0v[d] * sU[c*16 + d];
      ga0[n*16 + c] = s;
    }
  }
  #pragma unroll
  for (int off = 32; off; off >>= 1) site += __shfl_down(site, off, 64);
  int wave = threadIdx.x >> 6;
  if ((threadIdx.x & 63) == 0) swave[wave] = site;
  __syncthreads();
  if (threadIdx.x == 0)
    partials[blockIdx.x] = swave[0] + swave[1] + swave[2] + swave[3];
}

// Sum per-block partials into energy (single tiny block).
__global__ void k_energy(const float* __restrict__ partials, int nb,
                         float* __restrict__ energy)
{
  int t = threadIdx.x;           // 128 threads (2 waves)
  float s = 0.f;
  for (int i = t; i < nb; i += 128) s += partials[i];
  #pragma unroll
  for (int off = 32; off; off >>= 1) s += __shfl_down(s, off, 64);
  __shared__ float sw[2];
  if ((t & 63) == 0) sw[t >> 6] = s;
  __syncthreads();
  if (t == 0) energy[0] = sw[0] + sw[1];
}

// ---------------------------------------------------------------------------
// ga = g @ U^T (full, for block 0 backward)
// ---------------------------------------------------------------------------
__global__ void k_ga(const float* __restrict__ g0, const float* __restrict__ g1,
                     const float* __restrict__ g2, const float* __restrict__ U,
                     float* __restrict__ ga0, float* __restrict__ ga1, float* __restrict__ ga2,
                     int N)
{
  int idx = blockIdx.x * blockDim.x + threadIdx.x;
  int n = idx >> 4, c = idx & 15;
  if (n >= N) return;
  const float* U0 = U;
  const float* U1 = U + 256;
  const float* U2 = U + 512;
  float s = 0.f;
  #pragma unroll
  for (int d = 0; d < 16; d++) s += g0[n*16 + d] * U0[c*16 + d];
  ga0[n*16 + c] = s;
  float v1[3] = {0.f, 0.f, 0.f};
  #pragma unroll
  for (int d = 0; d < 16; d++) {
    float u = U1[c*16 + d];
    #pragma unroll
    for (int m = 0; m < 3; m++) v1[m] += g1[n*48 + d*3 + m] * u;
  }
  #pragma unroll
  for (int m = 0; m < 3; m++) ga1[n*48 + c*3 + m] = v1[m];
  float v2[5] = {0.f, 0.f, 0.f, 0.f, 0.f};
  #pragma unroll
  for (int d = 0; d < 16; d++) {
    float u = U2[c*16 + d];
    #pragma unroll
    for (int m = 0; m < 5; m++) v2[m] += g2[n*80 + d*5 + m] * u;
  }
  #pragma unroll
  for (int m = 0; m < 5; m++) ga2[n*80 + c*5 + m] = v2[m];
}

// ---------------------------------------------------------------------------
// Backward block 1, col-centric — wave per node (recompute rad/draddr; the
// streamed-precompute variant spilled and regressed, see r16 note).
// ---------------------------------------------------------------------------
__global__ void k_bwd_b1_col(const float* __restrict__ Wr, const float* __restrict__ br,
                             const float* __restrict__ h0_in, const float* __restrict__ h1_in,
                             const float* __restrict__ h2_in,
                             const float* __restrict__ ga0,
                             const float4* __restrict__ uC, const float2* __restrict__ scC,
                             const int* __restrict__ rowC,
                             const int* __restrict__ start_col, const int* __restrict__ deg_col,
                             float* __restrict__ g0, float* __restrict__ g1, float* __restrict__ g2,
                             float* __restrict__ dv_col, int N)
{
  int n = (blockIdx.x * blockDim.x + threadIdx.x) >> 6;
  int lane = threadIdx.x & 63;
  int g = lane >> 4, c = lane & 15;
  if (n >= N) return;
  float wr0[8], wr3[8], wr4[8];
  #pragma unroll
  for (int k = 0; k < 8; k++) {
    wr0[k] = Wr[k*80 + c];
    wr3[k] = Wr[k*80 + 48 + c];
    wr4[k] = Wr[k*80 + 64 + c];
  }
  float b0v = br[c], b3v = br[48 + c], b4v = br[64 + c];

  float h0c = h0_in[n*16 + c];
  float h1c[3], h2c[5];
  #pragma unroll
  for (int m = 0; m < 3; m++) h1c[m] = h1_in[n*48 + c*3 + m];
  #pragma unroll
  for (int m = 0; m < 5; m++) h2c[m] = h2_in[n*80 + c*5 + m];

  float accg0 = 0.f, accg1[3] = {0.f,0.f,0.f}, accg2[5] = {0.f,0.f,0.f,0.f,0.f};

  int i0 = start_col[n] + g, i1 = start_col[n] + deg_col[n];
  float4 Un = {0,0,0,0}; float2 SCn = {0,0};
  float dm0n = 0.f;
  if (i0 < i1) {
    Un = uC[i0]; SCn = scC[i0];
    dm0n = ga0[rowC[i0]*16 + c];
  }
  for (int i = i0; i < i1; i += 4) {
    float4 U = Un; float2 SC = SCn;
    float dm0 = dm0n;
    if (i+4 < i1) {
      Un = uC[i+4]; SCn = scC[i+4];
      dm0n = ga0[rowC[i+4]*16 + c];
    }
    float rad[8], draddr[8];
    rad_drad_from_sc(SC.x, SC.y, U.w, rad, draddr);
    float ux = U.x, uy = U.y, uz = U.z, inv_r = U.w;
    float sh1[3], sh2[5];
    sh_from_u(ux, uy, uz, sh1, sh2);

    float w0 = b0v, w3 = b3v, w4 = b4v;
    #pragma unroll
    for (int k = 0; k < 8; k++) {
      w0 += rad[k]*wr0[k]; w3 += rad[k]*wr3[k]; w4 += rad[k]*wr4[k];
    }

    float S1 = 0.f, S2 = 0.f;
    #pragma unroll
    for (int m = 0; m < 3; m++) S1 += h1c[m]*sh1[m];
    #pragma unroll
    for (int m = 0; m < 5; m++) S2 += h2c[m]*sh2[m];

    float dw0 = dm0 * h0c;
    float dw3 = dm0 * S1;
    float dw4 = dm0 * S2;
    float t3 = dm0 * w3, t4 = dm0 * w4;

    accg0 += dm0 * w0;
    #pragma unroll
    for (int m = 0; m < 3; m++) accg1[m] += t3 * sh1[m];
    #pragma unroll
    for (int m = 0; m < 5; m++) accg2[m] += t4 * sh2[m];

    float q1x = t3*h1c[0], q1y = t3*h1c[1], q1z = t3*h1c[2];
    float q0 = t4*h2c[0], q1 = t4*h2c[1], q2 = t4*h2c[2], q3 = t4*h2c[3], q4 = t4*h2c[4];
    float gr = 0.f;
    #pragma unroll
    for (int k = 0; k < 8; k++)
      gr += (dw0*wr0[k] + dw3*wr3[k] + dw4*wr4[k]) * draddr[k];
    float gux = SQRT3f*q1x + SQRT15f*(uy*q0 + uz*q3 + ux*q4);
    float guy = SQRT3f*q1y + SQRT15f*(ux*q0 + uz*q1 - uy*q4);
    float guz = SQRT3f*q1z + SQRT15f*uy*q1 + 3.f*SQRT5f*uz*q2 + SQRT15f*ux*q3;

    gr  = grp16_sum(gr);
    gux = grp16_sum(gux);
    guy = grp16_sum(guy);
    guz = grp16_sum(guz);

    if (c == 0) {
      float gdotu = gux*ux + guy*uy + guz*uz;
      dv_col[i*3+0] = gr*ux + (gux - gdotu*ux)*inv_r;
      dv_col[i*3+1] = gr*uy + (guy - gdotu*uy)*inv_r;
      dv_col[i*3+2] = gr*uz + (guz - gdotu*uz)*inv_r;
    }
  }
  accg0 = xgrp_sum(accg0);
  #pragma unroll
  for (int m = 0; m < 3; m++) accg1[m] = xgrp_sum(accg1[m]);
  #pragma unroll
  for (int m = 0; m < 5; m++) accg2[m] = xgrp_sum(accg2[m]);
  if (g == 0) {
    g0[n*16 + c] += accg0;
    #pragma unroll
    for (int m = 0; m < 3; m++) g1[n*48 + c*3 + m] = accg1[m];
    #pragma unroll
    for (int m = 0; m < 5; m++) g2[n*80 + c*5 + m] = accg2[m];
  }
}

// ---------------------------------------------------------------------------
// Backward block 0, row-centric — wave per node; dv written to dv_row stream.
// ---------------------------------------------------------------------------
__global__ void k_bwd_b0_row(const float* __restrict__ Wr, const float* __restrict__ br,
                             const float* __restrict__ h0_in,
                             const float* __restrict__ ga0, const float* __restrict__ ga1,
                             const float* __restrict__ ga2,
                             const float4* __restrict__ uR, const float2* __restrict__ scR,
                             const int* __restrict__ colR,
                             const int* __restrict__ start_row, const int* __restrict__ deg_row,
                             float* __restrict__ dv_row, int N)
{
  int n = (blockIdx.x * blockDim.x + threadIdx.x) >> 6;
  int lane = threadIdx.x & 63;
  int g = lane >> 4, c = lane & 15;
  if (n >= N) return;
  float wr0[8], wr1[8], wr2[8];
  #pragma unroll
  for (int k = 0; k < 8; k++) {
    wr0[k] = Wr[k*80 + c];
    wr1[k] = Wr[k*80 + 16 + c];
    wr2[k] = Wr[k*80 + 32 + c];
  }
  float b1v = br[16 + c], b2v = br[32 + c];

  float dm0 = ga0[n*16 + c];
  float dm1[3], dm2[5];
  #pragma unroll
  for (int m = 0; m < 3; m++) dm1[m] = ga1[n*48 + c*3 + m];
  #pragma unroll
  for (int m = 0; m < 5; m++) dm2[m] = ga2[n*80 + c*5 + m];

  int i0 = start_row[n] + g, i1 = start_row[n] + deg_row[n];
  float4 Un = {0,0,0,0}; float2 SCn = {0,0};
  float h0n = 0.f;
  if (i0 < i1) {
    Un = uR[i0]; SCn = scR[i0];
    h0n = h0_in[colR[i0]*16 + c];
  }
  for (int i = i0; i < i1; i += 4) {
    float4 U = Un; float2 SC = SCn;
    float h0c = h0n;
    if (i+4 < i1) {
      Un = uR[i+4]; SCn = scR[i+4];
      h0n = h0_in[colR[i+4]*16 + c];
    }
    float rad[8], draddr[8];
    rad_drad_from_sc(SC.x, SC.y, U.w, rad, draddr);
    float ux = U.x, uy = U.y, uz = U.z, inv_r = U.w;
    float sh1[3], sh2[5];
    sh_from_u(ux, uy, uz, sh1, sh2);

    float w1 = b1v, w2v = b2v;
    #pragma unroll
    for (int k = 0; k < 8; k++) { w1 += rad[k]*wr1[k]; w2v += rad[k]*wr2[k]; }

    float T1 = 0.f, T2 = 0.f;
    #pragma unroll
    for (int m = 0; m < 3; m++) T1 += dm1[m]*sh1[m];
    #pragma unroll
    for (int m = 0; m < 5; m++) T2 += dm2[m]*sh2[m];

    float dw0 = dm0 * h0c;
    float dw1 = h0c * T1;
    float dw2 = h0c * T2;

    float w1h = w1*h0c, w2h = w2v*h0c;
    float q1x = dm1[0]*w1h, q1y = dm1[1]*w1h, q1z = dm1[2]*w1h;
    float q0 = dm2[0]*w2h, q1 = dm2[1]*w2h, q2 = dm2[2]*w2h, q3 = dm2[3]*w2h, q4 = dm2[4]*w2h;

    float gr = 0.f;
    #pragma unroll
    for (int k = 0; k < 8; k++)
      gr += (dw0*wr0[k] + dw1*wr1[k] + dw2*wr2[k]) * draddr[k];
    float gux = SQRT3f*q1x + SQRT15f*(uy*q0 + uz*q3 + ux*q4);
    float guy = SQRT3f*q1y + SQRT15f*(ux*q0 + uz*q1 - uy*q4);
    float guz = SQRT3f*q1z + SQRT15f*uy*q1 + 3.f*SQRT5f*uz*q2 + SQRT15f*ux*q3;

    gr  = grp16_sum(gr);
    gux = grp16_sum(gux);
    guy = grp16_sum(guy);
    guz = grp16_sum(guz);

    if (c == 0) {
      float gdotu = gux*ux + guy*uy + guz*uz;
      dv_row[i*3+0] = gr*ux + (gux - gdotu*ux)*inv_r;
      dv_row[i*3+1] = gr*uy + (guy - gdotu*uy)*inv_r;
      dv_row[i*3+2] = gr*uz + (guz - gdotu*uz)*inv_r;
    }
  }
}

// ---------------------------------------------------------------------------
// Force assembly: dv_e = dv_col[colpos(e)] + dv_row[rowpos(e)].
// ---------------------------------------------------------------------------
__global__ void k_force(const int* __restrict__ start_row, const int* __restrict__ deg_row,
                        const int* __restrict__ cposR,
                        const int* __restrict__ start_col, const int* __restrict__ deg_col,
                        const int* __restrict__ rposC,
                        const float* __restrict__ dv_col, const float* __restrict__ dv_row,
                        float* __restrict__ force, int N)
{
  int n = blockIdx.x * blockDim.x + threadIdx.x;
  if (n >= N) return;
  float fx = 0.f, fy = 0.f, fz = 0.f;
  int c0 = start_col[n], c1 = c0 + deg_col[n];
  for (int i = c0; i < c1; i++) {
    int rp = rposC[i];
    fx += dv_col[i*3+0] + dv_row[rp*3+0];
    fy += dv_col[i*3+1] + dv_row[rp*3+1];
    fz += dv_col[i*3+2] + dv_row[rp*3+2];
  }
  int r0 = start_row[n], r1 = r0 + deg_row[n];
  for (int i = r0; i < r1; i++) {
    int cp = cposR[i];
    fx -= dv_row[i*3+0] + dv_col[cp*3+0];
    fy -= dv_row[i*3+1] + dv_col[cp*3+1];
    fz -= dv_row[i*3+2] + dv_col[cp*3+2];
  }
  force[n*3+0] = fx; force[n*3+1] = fy; force[n*3+2] = fz;
}

// ---------------------------------------------------------------------------
extern "C" void kernel_launch(void* const* d_in, const int* in_sizes, int n_in,
                              void* d_out, int out_size, void* d_ws, size_t ws_size,
                              hipStream_t stream)
{
  const float* pos    = (const float*)d_in[0];
  const int*   z      = (const int*)  d_in[1];
  const int*   ei     = (const int*)  d_in[2];
  const float* emb    = (const float*)d_in[3];
  const float* W_init = (const float*)d_in[4];
  const float* Wr     = (const float*)d_in[5];   // (2, 8, 80)
  const float* br     = (const float*)d_in[6];   // (2, 80)
  const float* W_out  = (const float*)d_in[7];   // (2, 3, 16, 16)
  const float* W_read = (const float*)d_in[8];
  const float* W1     = (const float*)d_in[9];
  const float* b1     = (const float*)d_in[10];
  const float* W2     = (const float*)d_in[11];
  const float* b2     = (const float*)d_in[12];

  const int N = in_sizes[0] / 3;
  const int E = in_sizes[2] / 2;

  const int BLK = 256;
  const int NPB = BLK / 64;  // nodes per block (wave-per-node kernels)
  const int NB_READOUT = cdiv(N, BLK);

  float* f = (float*)d_ws;
  float4* uR  = (float4*)f; f += (size_t)E*4;
  float4* uC  = (float4*)f; f += (size_t)E*4;
  float2* scR = (float2*)f; f += (size_t)E*2;
  float2* scC = (float2*)f; f += (size_t)E*2;
  float* h0_s0 = f; f += (size_t)N*16;
  float* h0_s1 = f; f += (size_t)N*16;
  float* h1_s1 = f; f += (size_t)N*48;
  float* h2_s1 = f; f += (size_t)N*80;
  float* a0    = f; f += (size_t)N*16;   // block-0 agg, then block-1 agg, then ga0_b0
  float* a1    = f; f += (size_t)N*48;   //                                 ga1_b0
  float* a2    = f; f += (size_t)N*80;   //                                 ga2_b0
  float* ga0b1 = f; f += (size_t)N*16;   // readout's ga0 (dE/da0 block 1)
  float* g0    = f; f += (size_t)N*16;
  float* g1    = f; f += (size_t)N*48;
  float* g2    = f; f += (size_t)N*80;
  float* dv_c  = f; f += (size_t)E*3;    // dv from bwd b1, col order
  float* dv_r  = f; f += (size_t)E*3;    // dv from bwd b0, row order
  float* partials = f; f += (size_t)NB_READOUT;
  int* ip = (int*)f;
  int* cursors   = ip; ip += 2;          // cursors+deg contiguous -> one memset
  int* deg_row   = ip; ip += N;
  int* deg_col   = ip; ip += N;
  int* start_row = ip; ip += N;
  int* start_col = ip; ip += N;
  int* cur_row   = ip; ip += N;
  int* cur_col   = ip; ip += N;
  int* colR      = ip; ip += E;
  int* cposR     = ip; ip += E;
  int* rowC      = ip; ip += E;
  int* rposC     = ip; ip += E;

  float* out    = (float*)d_out;
  float* energy = out;
  float* force  = out + 1;

  (void)hipMemsetAsync(cursors, 0, (size_t)(2 + 2*N) * sizeof(int), stream);

  // ---- CSR build (scan-free) + compact geometry in both orders ----
  k_hist<<<cdiv(E, BLK), BLK, 0, stream>>>(ei, E, deg_row, deg_col);
  k_alloc<<<cdiv(N, BLK), BLK, 0, stream>>>(deg_row, deg_col, start_row, cur_row,
                                            start_col, cur_col, cursors, N);
  k_scatter_geom<<<cdiv(E, BLK), BLK, 0, stream>>>(pos, ei, E, cur_row, cur_col,
                                                   uR, scR, uC, scC,
                                                   colR, cposR, rowC, rposC);

  k_node_init<<<cdiv(N, BLK), BLK, 0, stream>>>(emb, z, W_init, h0_s0, N);

  // ---- forward block 0 ----
  k_fwd_b0<<<cdiv(N, NPB), BLK, 0, stream>>>(Wr, br, h0_s0, uR, scR, colR,
                                             start_row, deg_row, a0, a1, a2, N);
  k_node_update<<<cdiv(N*16, BLK), BLK, 0, stream>>>(h0_s0, a0, a1, a2,
                                                     W_out, h0_s1, h1_s1, h2_s1, N);

  // ---- forward block 1 (h0_s2 folded into readout) ----
  k_fwd_b1<<<cdiv(N, NPB), BLK, 0, stream>>>(Wr + 640, br + 80,
                                             h0_s1, h1_s1, h2_s1, uR, scR, colR,
                                             start_row, deg_row, a0, N);

  // ---- readout fwd + bwd (includes block-1 h0 update; emits g0, ga0b1) ----
  k_readout_bwd<<<NB_READOUT, BLK, 0, stream>>>(h0_s1, a0, W_read, W1, b1, W2, b2,
                                                W_out + 768, g0, ga0b1, partials, N);
  k_energy<<<1, 128, 0, stream>>>(partials, NB_READOUT, energy);

  // ---- backward block 1 ----
  k_bwd_b1_col<<<cdiv(N, NPB), BLK, 0, stream>>>(Wr + 640, br + 80,
                                                 h0_s1, h1_s1, h2_s1, ga0b1,
                                                 uC, scC, rowC, start_col, deg_col,
                                                 g0, g1, g2, dv_c, N);

  // ---- backward block 0 ----
  k_ga<<<cdiv(N*16, BLK), BLK, 0, stream>>>(g0, g1, g2, W_out, a0, a1, a2, N);
  k_bwd_b0_row<<<cdiv(N, NPB), BLK, 0, stream>>>(Wr, br, h0_s0,
                                                 a0, a1, a2, uR, scR, colR,
                                                 start_row, deg_row, dv_r, N);

  // ---- force assembly ----
  k_force<<<cdiv(N, BLK), BLK, 0, stream>>>(start_row, deg_row, cposR,
                                            start_col, deg_col, rposC,
                                            dv_c, dv_r, force, N);
}